// Round 9
// baseline (379.105 us; speedup 1.0000x reference)
//
#include <hip/hip_runtime.h>
#include <hip/hip_bf16.h>
#include <math.h>
#include <stdint.h>

#define B_     32
#define HH_    28
#define WW_    28
#define N_     784
#define C_     384
#define M_     25088      // B_*N_
#define HEADS_ 8
#define HD_    48
#define HID_   1536

typedef __bf16 bf16;
typedef __attribute__((ext_vector_type(8))) __bf16 bf16x8;
typedef __attribute__((ext_vector_type(4))) __bf16 bf16x4;
typedef __attribute__((ext_vector_type(4))) float f32x4;

// async global->LDS, 16B per lane; LDS dest = wave-uniform base + lane*16
__device__ __forceinline__ void gload_lds16(const void* g, void* l) {
    __builtin_amdgcn_global_load_lds(
        (const __attribute__((address_space(1))) unsigned int*)g,
        (__attribute__((address_space(3))) unsigned int*)(uintptr_t)l,
        16, 0, 0);
}

// fast GELU (tanh form; max |err| vs exact erf-GELU ~3e-4 — far below bf16 rounding)
__device__ __forceinline__ float gelu_f(float x) {
    float u = 0.7978845608028654f * (x + 0.044715f * x * x * x);
    float e = __expf(-2.0f * fabsf(u));        // (0,1], never overflows
    float th = (1.f - e) / (1.f + e);
    th = copysignf(th, u);
    return 0.5f * x * (1.f + th);
}

// ---------------- weights fp32 -> bf16, all four in one launch ----------------
__global__ void convert4_kernel(const float* __restrict__ a, int na,
                                const float* __restrict__ b, int nb,
                                const float* __restrict__ c, int nc,
                                const float* __restrict__ d, int nd,
                                bf16* __restrict__ out) {
    int i = blockIdx.x * 256 + threadIdx.x;
    int j = i;
    const float* src;
    if (j < na) src = a + j;
    else { j -= na;
        if (j < nb) src = b + j;
        else { j -= nb;
            if (j < nc) src = c + j;
            else { j -= nc;
                if (j >= nd) return;
                src = d + j; } } }
    out[i] = (bf16)(*src);
}

// ---------------- CPE weight transpose: w[c][tap] -> wt[tap][c], both convs ---------
__global__ void wtrans_kernel(const float* __restrict__ w0, const float* __restrict__ w1,
                              float* __restrict__ wt0, float* __restrict__ wt1) {
    int i = blockIdx.x * 256 + threadIdx.x;     // 0..3455
    if (i >= C_ * 9) return;
    int c = i / 9, t = i - c * 9;
    wt0[t * C_ + c] = w0[i];
    wt1[t * C_ + c] = w1[i];
}

// ------- depthwise 3x3 conv + bias + residual, fused LayerNorm -> bf16 -------
// ONE WAVE PER ROW; shfl-butterfly LN (no barriers); XCD-chunk swizzle.
__global__ __launch_bounds__(256)
void cpe_ln_kernel(const float* __restrict__ x, const float* __restrict__ wt,
                   const float* __restrict__ bias, float* __restrict__ y,
                   const float* __restrict__ g, const float* __restrict__ beta,
                   bf16* __restrict__ lnout) {
    const int wave = threadIdx.x >> 6, lane = threadIdx.x & 63;
    const int f = blockIdx.x;
    const int row = (f & 7) * 3136 + (f >> 3) * 4 + wave;   // bijective over M_
    const int b = row / N_;
    const int n = row - b * N_;
    const int py = n / WW_, px = n - py * WW_;

    float acc[6], ctr[6];
    const float* xrow = x + (size_t)row * C_ + lane;
    #pragma unroll
    for (int j = 0; j < 6; j++) {
        acc[j] = bias[lane + j * 64];
        ctr[j] = xrow[j * 64];
    }

    if (py >= 1 && py <= 26 && px >= 1 && px <= 26) {
        const float* p = x + (size_t)(row - WW_ - 1) * C_ + lane;
        float v[9][6];
        #pragma unroll
        for (int t = 0; t < 9; t++) {
            if (t == 4) continue;
            const float* pt = p + ((t / 3) * WW_ + (t % 3)) * C_;
            #pragma unroll
            for (int j = 0; j < 6; j++) v[t][j] = pt[j * 64];
        }
        #pragma unroll
        for (int t = 0; t < 9; t++) {
            #pragma unroll
            for (int j = 0; j < 6; j++) {
                float xv = (t == 4) ? ctr[j] : v[t][j];
                acc[j] += wt[t * C_ + lane + j * 64] * xv;
            }
        }
    } else {
        #pragma unroll
        for (int t = 0; t < 9; t++) {
            int yy = py + t / 3 - 1, xx = px + t % 3 - 1;
            if (yy < 0 || yy >= HH_ || xx < 0 || xx >= WW_) continue;
            const float* pt = x + (size_t)(b * N_ + yy * WW_ + xx) * C_ + lane;
            #pragma unroll
            for (int j = 0; j < 6; j++)
                acc[j] += wt[t * C_ + lane + j * 64] * pt[j * 64];
        }
    }
    #pragma unroll
    for (int j = 0; j < 6; j++) acc[j] += ctr[j];

    float* yrow = y + (size_t)row * C_ + lane;
    #pragma unroll
    for (int j = 0; j < 6; j++) yrow[j * 64] = acc[j];

    float s = 0.f;
    #pragma unroll
    for (int j = 0; j < 6; j++) s += acc[j];
    #pragma unroll
    for (int off = 1; off < 64; off <<= 1) s += __shfl_xor(s, off, 64);
    float mean = s * (1.f / C_);
    float d[6], vs = 0.f;
    #pragma unroll
    for (int j = 0; j < 6; j++) { d[j] = acc[j] - mean; vs += d[j] * d[j]; }
    #pragma unroll
    for (int off = 1; off < 64; off <<= 1) vs += __shfl_xor(vs, off, 64);
    float rstd = rsqrtf(vs * (1.f / C_) + 1e-5f);
    bf16* lrow = lnout + (size_t)row * C_ + lane;
    #pragma unroll
    for (int j = 0; j < 6; j++) {
        int c = lane + j * 64;
        lrow[j * 64] = (bf16)(d[j] * rstd * g[c] + beta[c]);
    }
}

// -------- bf16 MFMA GEMM: 3-stage ring + raw barrier/vmcnt + XOR bank swizzle ------
// LDS rows are 64B (unpadded, required by global_load_lds) -> naive b128 fragment
// reads are 8-way bank-conflicted. Fix: at staging, lane loads global k-part
// p = (lane&3) ^ ((row>>1)&3) (same 64B segment -> coalescing unchanged); read
// side uses slot quad ^ ((r>>1)&3). Within a quad the 16 lanes then hit all 8
// 16B bank-groups at 2 lanes each = conflict-free (m136: 2-way is free).
template<bool BIAS, bool GELU, bool RESID, bool OUTBF>
__global__ __launch_bounds__(256)
void gemm_kernel(const bf16* __restrict__ A, const bf16* __restrict__ Wt,
                 const float* __restrict__ bias, const float* __restrict__ resid,
                 void* __restrict__ outp, int M, int N, int K) {
    __shared__ __align__(16) bf16 As[3 * 4096];
    __shared__ __align__(16) bf16 Bs[3 * 4096];

    const int nbn = gridDim.x, nbm = gridDim.y;
    const int f = blockIdx.y * nbn + blockIdx.x;
    const int grp = f / (8 * nbn);
    const int rem = f - grp * 8 * nbn;
    const int rows = min(8, nbm - grp * 8);
    const int bm = (grp * 8 + rem % rows) * 128;
    const int bn = (rem / rows) * 128;

    const int t = threadIdx.x;
    const int wave = t >> 6, lane = t & 63;
    const int wm = (wave & 1) * 64, wn = (wave >> 1) * 64;
    const int quad = lane >> 4, r = lane & 15;

    // staging: wave w covers tile rows [w*32, w*32+32); lane i -> LDS base + 16B*i
    const int ldrow = lane >> 2;
    const int part  = (lane & 3) ^ ((ldrow >> 1) & 3);   // XOR swizzle
    const int ldcol = part * 8;
    const bf16* ga0 = A  + (size_t)(bm + wave * 32 + ldrow) * K + ldcol;
    const bf16* ga1 = ga0 + (size_t)16 * K;              // (+16 rows: (row>>1)&3 unchanged)
    const bf16* gb0 = Wt + (size_t)(bn + wave * 32 + ldrow) * K + ldcol;
    const bf16* gb1 = gb0 + (size_t)16 * K;
    const int lbase = wave * 32 * 32;

    // fragment-read slot offset (per-lane constant)
    const int slotA = (quad ^ ((r >> 1) & 3)) * 8;

    f32x4 acc[4][4] = {};

    gload_lds16(ga0, &As[lbase]);
    gload_lds16(ga1, &As[lbase + 512]);
    gload_lds16(gb0, &Bs[lbase]);
    gload_lds16(gb1, &Bs[lbase + 512]);
    gload_lds16(ga0 + 32, &As[4096 + lbase]);
    gload_lds16(ga1 + 32, &As[4096 + lbase + 512]);
    gload_lds16(gb0 + 32, &Bs[4096 + lbase]);
    gload_lds16(gb1 + 32, &Bs[4096 + lbase + 512]);

    int buf = 0;
    int k0 = 0;
    for (; k0 < K - 32; k0 += 32) {
        asm volatile("s_waitcnt vmcnt(4)" ::: "memory");
        asm volatile("s_barrier" ::: "memory");
        if (k0 + 64 < K) {
            const int nb3 = (buf == 0 ? 2 : buf - 1) * 4096;   // (buf+2)%3
            gload_lds16(ga0 + k0 + 64, &As[nb3 + lbase]);
            gload_lds16(ga1 + k0 + 64, &As[nb3 + lbase + 512]);
            gload_lds16(gb0 + k0 + 64, &Bs[nb3 + lbase]);
            gload_lds16(gb1 + k0 + 64, &Bs[nb3 + lbase + 512]);
        }
        const bf16* as = &As[buf * 4096];
        const bf16* bs = &Bs[buf * 4096];
        bf16x8 af[4], bfr[4];
        #pragma unroll
        for (int i = 0; i < 4; i++)
            af[i] = *(const bf16x8*)(&as[(wm + i * 16 + r) * 32 + slotA]);
        #pragma unroll
        for (int j = 0; j < 4; j++)
            bfr[j] = *(const bf16x8*)(&bs[(wn + j * 16 + r) * 32 + slotA]);
        #pragma unroll
        for (int i = 0; i < 4; i++)
            #pragma unroll
            for (int j = 0; j < 4; j++)
                acc[i][j] = __builtin_amdgcn_mfma_f32_16x16x32_bf16(af[i], bfr[j], acc[i][j], 0, 0, 0);
        buf = (buf == 2) ? 0 : buf + 1;
    }
    {
        asm volatile("s_waitcnt vmcnt(0)" ::: "memory");
        asm volatile("s_barrier" ::: "memory");
        const bf16* as = &As[buf * 4096];
        const bf16* bs = &Bs[buf * 4096];
        bf16x8 af[4], bfr[4];
        #pragma unroll
        for (int i = 0; i < 4; i++)
            af[i] = *(const bf16x8*)(&as[(wm + i * 16 + r) * 32 + slotA]);
        #pragma unroll
        for (int j = 0; j < 4; j++)
            bfr[j] = *(const bf16x8*)(&bs[(wn + j * 16 + r) * 32 + slotA]);
        #pragma unroll
        for (int i = 0; i < 4; i++)
            #pragma unroll
            for (int j = 0; j < 4; j++)
                acc[i][j] = __builtin_amdgcn_mfma_f32_16x16x32_bf16(af[i], bfr[j], acc[i][j], 0, 0, 0);
    }

    #pragma unroll
    for (int i = 0; i < 4; i++) {
        #pragma unroll
        for (int j = 0; j < 4; j++) {
            int n = bn + wn + j * 16 + r;
            float bv = BIAS ? bias[n] : 0.f;
            #pragma unroll
            for (int e = 0; e < 4; e++) {
                int m = bm + wm + i * 16 + quad * 4 + e;
                float val = acc[i][j][e] + bv;
                if (GELU) val = gelu_f(val);
                if (RESID) val += resid[(size_t)m * N + n];
                if (OUTBF) ((bf16*)outp)[(size_t)m * N + n] = (bf16)val;
                else       ((float*)outp)[(size_t)m * N + n] = val;
            }
        }
    }
}

// ---------------- fused channel attention (scores + softmax + apply), MFMA ----------
__global__ __launch_bounds__(256)
void attn_fused_kernel(const bf16* __restrict__ qkvb, bf16* __restrict__ outp) {
    __shared__ __align__(16) bf16 stage[4][3872];
    __shared__ float Sred[4][48][49];
    __shared__ __align__(16) bf16 attn_s[48 * 72];

    const int bh = blockIdx.x;
    const int b = bh >> 3, h = bh & 7;
    const int t = threadIdx.x;
    const int wave = t >> 6, lane = t & 63;
    const int quad = lane >> 4, r = lane & 15;
    const int tensor = lane >> 5;
    const int n_local = lane & 31;

    const size_t qkv_base = (size_t)b * N_ * 1152;
    const int toff = 384 + tensor * 384 + h * 48;

    f32x4 acc[3][3] = {};
    bf16* kT = &stage[wave][0];
    bf16* vT = &stage[wave][1936];
    bf16* myT = &stage[wave][tensor * 1936];

    for (int c = wave; c < 25; c += 4) {
        int n0 = c * 32;
        bf16 rowbuf[48];
        if (n0 + n_local < N_) {
            const uint4* src = (const uint4*)(qkvb + qkv_base + (size_t)(n0 + n_local) * 1152 + toff);
            #pragma unroll
            for (int i = 0; i < 6; i++) *(uint4*)(&rowbuf[i * 8]) = src[i];
        } else {
            #pragma unroll
            for (int i = 0; i < 48; i++) rowbuf[i] = (bf16)0.f;
        }
        #pragma unroll
        for (int d = 0; d < 48; d++) myT[d * 40 + n_local] = rowbuf[d];
        bf16x8 af[3], bfv[3];
        #pragma unroll
        for (int i = 0; i < 3; i++) af[i]  = *(const bf16x8*)(&kT[(i * 16 + r) * 40 + quad * 8]);
        #pragma unroll
        for (int j = 0; j < 3; j++) bfv[j] = *(const bf16x8*)(&vT[(j * 16 + r) * 40 + quad * 8]);
        #pragma unroll
        for (int i = 0; i < 3; i++)
            #pragma unroll
            for (int j = 0; j < 3; j++)
                acc[i][j] = __builtin_amdgcn_mfma_f32_16x16x32_bf16(af[i], bfv[j], acc[i][j], 0, 0, 0);
    }

    #pragma unroll
    for (int i = 0; i < 3; i++)
        #pragma unroll
        for (int j = 0; j < 3; j++)
            #pragma unroll
            for (int e = 0; e < 4; e++)
                Sred[wave][i * 16 + quad * 4 + e][j * 16 + r] = acc[i][j][e];
    __syncthreads();

    if (t < 48) {
        float row[48];
        float mx = -1e30f;
        #pragma unroll
        for (int e = 0; e < 48; e++) {
            float s = Sred[0][t][e] + Sred[1][t][e] + Sred[2][t][e] + Sred[3][t][e];
            s *= 0.14433756729740644f;
            row[e] = s;
            mx = fmaxf(mx, s);
        }
        float sum = 0.f;
        #pragma unroll
        for (int e = 0; e < 48; e++) { float ex = __expf(row[e] - mx); row[e] = ex; sum += ex; }
        float inv = 1.f / sum;
        #pragma unroll
        for (int e = 0; e < 48; e++) attn_s[t * 72 + e] = (bf16)(row[e] * inv);
        #pragma unroll
        for (int e = 48; e < 64; e++) attn_s[t * 72 + e] = (bf16)0.f;
    }
    __syncthreads();

    const bf16* qbase = qkvb + qkv_base + h * 48;
    for (int nt = wave; nt < 49; nt += 4) {
        int n0 = nt * 16;
        f32x4 oacc[3] = {};
        #pragma unroll
        for (int kc = 0; kc < 2; kc++) {
            bf16x8 bq = *(const bf16x8*)(qbase + (size_t)(n0 + r) * 1152 + kc * 32 + quad * 8);
            #pragma unroll
            for (int i = 0; i < 3; i++) {
                bf16x8 aa = *(const bf16x8*)(&attn_s[(i * 16 + r) * 72 + kc * 32 + quad * 8]);
                oacc[i] = __builtin_amdgcn_mfma_f32_16x16x32_bf16(aa, bq, oacc[i], 0, 0, 0);
            }
        }
        #pragma unroll
        for (int i = 0; i < 3; i++) {
            bf16x4 ov;
            #pragma unroll
            for (int e = 0; e < 4; e++) ov[e] = (bf16)oacc[i][e];
            *(bf16x4*)(outp + (size_t)(b * N_ + n0 + r) * 384 + h * 48 + i * 16 + quad * 4) = ov;
        }
    }
}

// ---------------- launch ----------------
extern "C" void kernel_launch(void* const* d_in, const int* in_sizes, int n_in,
                              void* d_out, int out_size, void* d_ws, size_t ws_size,
                              hipStream_t stream) {
    const float* x      = (const float*)d_in[0];
    const float* cpe0_w = (const float*)d_in[3];
    const float* cpe0_b = (const float*)d_in[4];
    const float* cpe1_w = (const float*)d_in[5];
    const float* cpe1_b = (const float*)d_in[6];
    const float* n1g    = (const float*)d_in[7];
    const float* n1b    = (const float*)d_in[8];
    const float* qkv_w  = (const float*)d_in[9];
    const float* proj_w = (const float*)d_in[10];
    const float* proj_b = (const float*)d_in[11];
    const float* n2g    = (const float*)d_in[12];
    const float* n2b    = (const float*)d_in[13];
    const float* fc1_w  = (const float*)d_in[14];
    const float* fc1_b  = (const float*)d_in[15];
    const float* fc2_w  = (const float*)d_in[16];
    const float* fc2_b  = (const float*)d_in[17];

    char* ws = (char*)d_ws;
    size_t off = 0;
    bf16* cur    = (bf16*)(ws + off); off += (size_t)M_ * C_ * 2;
    bf16* qkvb   = (bf16*)(ws + off);
    float* x3    = (float*)qkvb;
    off += (size_t)M_ * 1152 * 2;
    bf16* hbuf   = (bf16*)(ws + off); off += (size_t)M_ * HID_ * 2;
    bf16* qkv_wb  = (bf16*)(ws + off); off += (size_t)1152 * 384 * 2;
    bf16* proj_wb = (bf16*)(ws + off); off += (size_t)384 * 384 * 2;
    bf16* fc1_wb  = (bf16*)(ws + off); off += (size_t)HID_ * 384 * 2;
    bf16* fc2_wb  = (bf16*)(ws + off); off += (size_t)384 * HID_ * 2;
    float* wt0    = (float*)(ws + off); off += (size_t)C_ * 9 * 4;
    float* wt1    = (float*)(ws + off); off += (size_t)C_ * 9 * 4;
    float* out = (float*)d_out;   // doubles as x1/x2 trunk buffer

    const int na = 442368, nb = 147456, nc = 589824, nd = 589824;
    convert4_kernel<<<(na + nb + nc + nd + 255) / 256, 256, 0, stream>>>(
        qkv_w, na, proj_w, nb, fc1_w, nc, fc2_w, nd, qkv_wb);
    wtrans_kernel<<<(C_ * 9 + 255) / 256, 256, 0, stream>>>(cpe0_w, cpe1_w, wt0, wt1);

    // CPE0 + LN1: x -> out (x1, fp32) and cur (bf16)
    cpe_ln_kernel<<<M_ / 4, 256, 0, stream>>>(x, wt0, cpe0_b, out, n1g, n1b, cur);
    // qkv: cur @ qkv_w^T -> qkvb  (M x 1152, K=384)
    gemm_kernel<false, false, false, true><<<dim3(1152 / 128, M_ / 128), 256, 0, stream>>>(
        cur, qkv_wb, nullptr, nullptr, qkvb, M_, 1152, 384);
    // fused channel attention -> cur
    attn_fused_kernel<<<256, 256, 0, stream>>>(qkvb, cur);
    // proj + bias + residual -> out (fp32)
    gemm_kernel<true, false, true, false><<<dim3(384 / 128, M_ / 128), 256, 0, stream>>>(
        cur, proj_wb, proj_b, out, out, M_, 384, 384);
    // CPE1 + LN2: out (x2) -> x3 (fp32) and cur (bf16)
    cpe_ln_kernel<<<M_ / 4, 256, 0, stream>>>(out, wt1, cpe1_b, x3, n2g, n2b, cur);
    // fc1 + bias + gelu -> hbuf (bf16), M x 1536, K=384
    gemm_kernel<true, true, false, true><<<dim3(HID_ / 128, M_ / 128), 256, 0, stream>>>(
        cur, fc1_wb, fc1_b, nullptr, hbuf, M_, HID_, 384);
    // fc2 + bias + residual x3 -> d_out (fp32), M x 384, K=1536
    gemm_kernel<true, false, true, false><<<dim3(384 / 128, M_ / 128), 256, 0, stream>>>(
        hbuf, fc2_wb, fc2_b, x3, out, M_, 384, HID_);
}